// Round 15
// baseline (52.739 us; speedup 1.0000x reference)
//
#include <hip/hip_runtime.h>
#include <hip/hip_bf16.h>

#define T_ 4096
#define D_ 512
#define H_ 8
#define BAND 16
#define G1_K 512

typedef float f32x4 __attribute__((ext_vector_type(4)));
typedef __bf16 bf16x8 __attribute__((ext_vector_type(8)));
typedef unsigned short us8 __attribute__((ext_vector_type(8)));
typedef unsigned short us4 __attribute__((ext_vector_type(4)));

__device__ __forceinline__ unsigned short f2b(float f) {
  union { float f; unsigned u; } v; v.f = f;
  unsigned r = v.u + 0x7fffu + ((v.u >> 16) & 1u);
  return (unsigned short)(r >> 16);
}

__device__ __forceinline__ f32x4 mfma16(bf16x8 a, bf16x8 b, f32x4 c) {
  return __builtin_amdgcn_mfma_f32_16x16x32_bf16(a, b, c, 0, 0, 0);
}

#define GLD16(gp, lp) __builtin_amdgcn_global_load_lds( \
    (const __attribute__((address_space(1))) void*)(gp), \
    (__attribute__((address_space(3))) void*)(lp), 16, 0, 0)

// ---------------- fused: weight fp32->bf16 cvt + LayerNorm ----------------
__global__ __launch_bounds__(256) void prep_k(const float* __restrict__ x,
                                              const float* __restrict__ g,
                                              const float* __restrict__ bt,
                                              const float* __restrict__ win,
                                              const float* __restrict__ wout,
                                              unsigned short* __restrict__ h,
                                              unsigned short* __restrict__ winb,
                                              unsigned short* __restrict__ woutb) {
  int bx = blockIdx.x;
  if (bx >= 2048) {
    int i = (bx - 2048) * 256 + threadIdx.x;
    const int n1 = 3 * D_ * D_ / 4;
    if (i < n1) {
      float4 v = ((const float4*)win)[i];
      us4 o; o.x = f2b(v.x); o.y = f2b(v.y); o.z = f2b(v.z); o.w = f2b(v.w);
      ((us4*)winb)[i] = o;
    } else {
      int j = i - n1;
      float4 v = ((const float4*)wout)[j];
      us4 o; o.x = f2b(v.x); o.y = f2b(v.y); o.z = f2b(v.z); o.w = f2b(v.w);
      ((us4*)woutb)[j] = o;
    }
    return;
  }
  int wave = threadIdx.x >> 6, lane = threadIdx.x & 63;
  size_t row = (size_t)bx * 4 + wave;
  const float4* xr = (const float4*)(x + row * D_);
  float4 a = xr[lane * 2], b = xr[lane * 2 + 1];
  float s = a.x + a.y + a.z + a.w + b.x + b.y + b.z + b.w;
  #pragma unroll
  for (int o = 32; o; o >>= 1) s += __shfl_xor(s, o, 64);
  float mu = s * (1.0f / D_);
  float d0 = a.x - mu, d1 = a.y - mu, d2 = a.z - mu, d3 = a.w - mu;
  float d4 = b.x - mu, d5 = b.y - mu, d6 = b.z - mu, d7 = b.w - mu;
  float q = d0*d0 + d1*d1 + d2*d2 + d3*d3 + d4*d4 + d5*d5 + d6*d6 + d7*d7;
  #pragma unroll
  for (int o = 32; o; o >>= 1) q += __shfl_xor(q, o, 64);
  float rstd = rsqrtf(q * (1.0f / D_) + 1e-5f);
  const float4* gr = (const float4*)g;
  const float4* br = (const float4*)bt;
  float4 g0 = gr[lane * 2], g1 = gr[lane * 2 + 1];
  float4 b0 = br[lane * 2], b1 = br[lane * 2 + 1];
  us8 o8;
  o8[0] = f2b(d0 * rstd * g0.x + b0.x);
  o8[1] = f2b(d1 * rstd * g0.y + b0.y);
  o8[2] = f2b(d2 * rstd * g0.z + b0.z);
  o8[3] = f2b(d3 * rstd * g0.w + b0.w);
  o8[4] = f2b(d4 * rstd * g1.x + b1.x);
  o8[5] = f2b(d5 * rstd * g1.y + b1.y);
  o8[6] = f2b(d6 * rstd * g1.z + b1.z);
  o8[7] = f2b(d7 * rstd * g1.w + b1.w);
  *((us8*)(h + row * D_) + lane) = o8;
}

// ============ GEMM1: 4-phase 256x192 BK=64, 8 waves, 256 blocks ============
#define SLOT_SZ 28672

__device__ __forceinline__ void stgA(const unsigned short* __restrict__ gb,
                                     unsigned short* lds, int slot, int h, int tt,
                                     int rl0, int u0, int su) {
  #pragma unroll
  for (int j = 0; j < 2; ++j) {
    int row = h * 128 + rl0 + 64 * j;
    GLD16(gb + (size_t)row * G1_K + tt * 64 + su, lds + slot * SLOT_SZ + row * 64 + u0 * 8);
  }
}
__device__ __forceinline__ void stgB(const unsigned short* __restrict__ gb,
                                     unsigned short* lds, int slot, int tt,
                                     int rl0, int u0, int su) {
  #pragma unroll
  for (int c = 0; c < 3; ++c) {
    int row = c * 64 + rl0;
    GLD16(gb + (size_t)row * G1_K + tt * 64 + su, lds + slot * SLOT_SZ + 16384 + row * 64 + u0 * 8);
  }
}

#define VMC6 asm volatile("s_waitcnt vmcnt(6)" ::: "memory")
#define VMC5 asm volatile("s_waitcnt vmcnt(5)" ::: "memory")
#define VMC4 asm volatile("s_waitcnt vmcnt(4)" ::: "memory")
#define VMC3 asm volatile("s_waitcnt vmcnt(3)" ::: "memory")
#define VMC2 asm volatile("s_waitcnt vmcnt(2)" ::: "memory")
#define VMC0 asm volatile("s_waitcnt vmcnt(0)" ::: "memory")

// PH in {0,1}: m-frags 4*PH..4*PH+3. B-frags loaded at PH==0.
#define PHASE4(SLOT, PH, STAGE_STMT, WAIT_STMT) do {                                       \
    if ((PH) == 0) {                                                                       \
      _Pragma("unroll") for (int nf = 0; nf < 3; ++nf) {                                   \
        breg[nf][0] = *(const bf16x8*)(lds + (SLOT)*SLOT_SZ + boff + nf*1024 + swz0);      \
        breg[nf][1] = *(const bf16x8*)(lds + (SLOT)*SLOT_SZ + boff + nf*1024 + swz1);      \
      }                                                                                    \
    }                                                                                      \
    bf16x8 aA[4][2];                                                                       \
    _Pragma("unroll") for (int mi = 0; mi < 4; ++mi) {                                     \
      aA[mi][0] = *(const bf16x8*)(lds + (SLOT)*SLOT_SZ + aoff + (4*(PH)+mi)*1024 + swz0); \
      aA[mi][1] = *(const bf16x8*)(lds + (SLOT)*SLOT_SZ + aoff + (4*(PH)+mi)*1024 + swz1); \
    }                                                                                      \
    STAGE_STMT;                                                                            \
    __builtin_amdgcn_s_barrier();                                                          \
    asm volatile("s_waitcnt lgkmcnt(0)" ::: "memory");                                     \
    __builtin_amdgcn_sched_barrier(0);                                                     \
    __builtin_amdgcn_s_setprio(1);                                                         \
    _Pragma("unroll") for (int mi = 0; mi < 4; ++mi)                                       \
      _Pragma("unroll") for (int nf = 0; nf < 3; ++nf) {                                   \
        acc[4*(PH)+mi][nf] = mfma16(aA[mi][0], breg[nf][0], acc[4*(PH)+mi][nf]);           \
        acc[4*(PH)+mi][nf] = mfma16(aA[mi][1], breg[nf][1], acc[4*(PH)+mi][nf]);           \
      }                                                                                    \
    __builtin_amdgcn_s_setprio(0);                                                         \
    __builtin_amdgcn_sched_barrier(0);                                                     \
    WAIT_STMT;                                                                             \
    __builtin_amdgcn_s_barrier();                                                          \
  } while (0)

__global__ __launch_bounds__(512, 2) void gemm_qkv8(const unsigned short* __restrict__ A,
                                                    const unsigned short* __restrict__ Bw,
                                                    const float* __restrict__ bias,
                                                    unsigned short* __restrict__ C) {
  extern __shared__ char smem[];
  unsigned short* lds = (unsigned short*)smem;
  int tid = threadIdx.x;
  int lane = tid & 63, wave = tid >> 6;
  int wm = wave >> 2, wn = wave & 3;
  int fr = lane & 15, fq = lane >> 4;
  int d = blockIdx.x;
  int l = (d & 7) * 32 + (d >> 3);
  int bm = l >> 3, bn = l & 7;

  const unsigned short* Ag = A + (size_t)bm * 256 * G1_K;
  const unsigned short* Bg = Bw + (size_t)bn * 192 * G1_K;

  int rl0 = tid >> 3, u0 = tid & 7;
  int su = (u0 ^ (rl0 & 7)) * 8;

  int aoff = wm * 8192 + fr * 64;
  int boff = 16384 + (wn * 48 + fr) * 64;
  int swz0 = (fq ^ (fr & 7)) * 8;
  int swz1 = ((4 + fq) ^ (fr & 7)) * 8;

  f32x4 acc[8][3] = {};
  bf16x8 breg[3][2];

  stgB(Bg, lds, 0, 0, rl0, u0, su);
  stgA(Ag, lds, 0, 0, 0, rl0, u0, su);
  stgA(Ag, lds, 0, 1, 0, rl0, u0, su);
  stgB(Bg, lds, 1, 1, rl0, u0, su);
  VMC3;
  __builtin_amdgcn_s_barrier();

  #pragma unroll 1
  for (int i = 0; i < 3; ++i) {
    int t = 2 * i;
    PHASE4(0, 0, { stgA(Ag, lds, 1, 0, t + 1, rl0, u0, su);
                   stgA(Ag, lds, 1, 1, t + 1, rl0, u0, su); }, (void)0);
    PHASE4(0, 1, stgB(Bg, lds, 0, t + 2, rl0, u0, su), VMC3);
    PHASE4(1, 0, { stgA(Ag, lds, 0, 0, t + 2, rl0, u0, su);
                   stgA(Ag, lds, 0, 1, t + 2, rl0, u0, su); }, (void)0);
    PHASE4(1, 1, stgB(Bg, lds, 1, t + 3, rl0, u0, su), VMC3);
  }
  // tail: tiles 6,7
  PHASE4(0, 0, { stgA(Ag, lds, 1, 0, 7, rl0, u0, su);
                 stgA(Ag, lds, 1, 1, 7, rl0, u0, su); }, (void)0);
  PHASE4(0, 1, (void)0, VMC0);
  PHASE4(1, 0, (void)0, (void)0);
  PHASE4(1, 1, (void)0, (void)0);

  // epilogue: acc -> LDS bf16 [256][192] -> head-major coalesced stores
  int rl = wm * 128 + fq * 4;
  int cl = wn * 48 + fr;
  float bv[3];
  #pragma unroll
  for (int nf = 0; nf < 3; ++nf) bv[nf] = bias[bn * 192 + cl + nf * 16];
  __syncthreads();
  #pragma unroll
  for (int mf = 0; mf < 8; ++mf)
    #pragma unroll
    for (int nf = 0; nf < 3; ++nf)
      #pragma unroll
      for (int r = 0; r < 4; ++r)
        lds[(rl + mf * 16 + r) * 192 + cl + nf * 16] = f2b(acc[mf][nf][r] + bv[nf]);
  __syncthreads();
  int bb0 = (bm * 256) >> 12;
  int t00 = (bm * 256) & 4095;
  #pragma unroll
  for (int it = 0; it < 12; ++it) {
    int idx = it * 512 + tid;
    int row = idx / 24;
    int u = idx % 24;
    us8 v = *(const us8*)(lds + row * 192 + u * 8);
    int hs = bn * 3 + (u >> 3);
    int sec = hs >> 3, hd = hs & 7;
    size_t dst = ((size_t)(sec * 16 + bb0 * 8 + hd) * T_ + t00 + row) * 64 + (u & 7) * 8;
    *(us8*)(C + dst) = v;
  }
}

// ---------------- GEMM2: 128x128, 512 threads, 2-slot prefetch + spread x-prefetch ----------------
// Fully unrolled K-loop; per-tile one float4 x-load so the 16MB x-read streams during
// compute instead of bursting in the epilogue. vmcnt ledger re-derived (in-order retire):
// prologue VMC4; kt0 VMC5; kt1-5 VMC6; kt6 VMC2; epilogue xv waits compiler-inserted.
__global__ __launch_bounds__(512) void gemm_bt2(const unsigned short* __restrict__ A,
                                                const unsigned short* __restrict__ Bw,
                                                const float* __restrict__ bias,
                                                const float* __restrict__ xres,
                                                float* __restrict__ ofp,
                                                int N, int K) {
  __shared__ unsigned short AB[4 * 128 * 64];
  unsigned short* As = AB;
  unsigned short* Bs = AB + 16384;
  int tid = threadIdx.x;
  int lane = tid & 63;
  int wave = tid >> 6;
  int wm = wave >> 2, wn = wave & 3;
  int fr = lane & 15, fq = lane >> 4;
  int dd = blockIdx.x;
  int nbn = N >> 7;
  int l = (dd & 7) * (gridDim.x >> 3) + (dd >> 3);
  int bm = l / nbn, bn = l % nbn;

  const unsigned short* Ap[2];
  const unsigned short* Bp[2];
  int loff[2];
  #pragma unroll
  for (int g = 0; g < 2; ++g) {
    int s = g * 512 + tid;
    int row = s >> 3, u = s & 7;
    int uu = u ^ (row & 7);
    Ap[g] = A + (size_t)(bm * 128 + row) * K + uu * 8;
    Bp[g] = Bw + (size_t)(bn * 128 + row) * K + uu * 8;
    loff[g] = s * 16;
  }
  int xrow = tid >> 5, xcu = tid & 31;       // this thread's x/out chunk geometry
  const float* xbase = xres + (size_t)(bm * 128 + xrow) * N + bn * 128 + xcu * 4;

  f32x4 acc[4][2] = {};
  float4 xv[8];

  #pragma unroll
  for (int g = 0; g < 2; ++g) GLD16(Ap[g], (char*)As + loff[g]);
  #pragma unroll
  for (int g = 0; g < 2; ++g) GLD16(Bp[g], (char*)Bs + loff[g]);
  #pragma unroll
  for (int g = 0; g < 2; ++g) GLD16(Ap[g] + 64, (char*)As + 16384 + loff[g]);
  #pragma unroll
  for (int g = 0; g < 2; ++g) GLD16(Bp[g] + 64, (char*)Bs + 16384 + loff[g]);
  VMC4;
  __builtin_amdgcn_s_barrier();

  #pragma unroll
  for (int kt = 0; kt < 8; ++kt) {
    int sl = (kt & 1) * 8192;
    bf16x8 af[4], bfr[2];
    #pragma unroll
    for (int i2 = 0; i2 < 4; ++i2) {
      int row = wm * 64 + i2 * 16 + fr;
      af[i2] = *(const bf16x8*)(As + sl + row * 64 + ((fq ^ (fr & 7)) << 3));
    }
    #pragma unroll
    for (int j = 0; j < 2; ++j) {
      int row = wn * 32 + j * 16 + fr;
      bfr[j] = *(const bf16x8*)(Bs + sl + row * 64 + ((fq ^ (fr & 7)) << 3));
    }
    #pragma unroll
    for (int i2 = 0; i2 < 4; ++i2)
      #pragma unroll
      for (int j = 0; j < 2; ++j)
        acc[i2][j] = mfma16(af[i2], bfr[j], acc[i2][j]);
    bf16x8 af1[4], bfr1[2];
    #pragma unroll
    for (int i2 = 0; i2 < 4; ++i2) {
      int row = wm * 64 + i2 * 16 + fr;
      af1[i2] = *(const bf16x8*)(As + sl + row * 64 + (((4 + fq) ^ (fr & 7)) << 3));
    }
    #pragma unroll
    for (int j = 0; j < 2; ++j) {
      int row = wn * 32 + j * 16 + fr;
      bfr1[j] = *(const bf16x8*)(Bs + sl + row * 64 + (((4 + fq) ^ (fr & 7)) << 3));
    }
    asm volatile("s_waitcnt lgkmcnt(0)" ::: "memory");
    __builtin_amdgcn_sched_barrier(0);
    __builtin_amdgcn_s_barrier();            // all waves done reading this slot
    if (kt < 6) {
      int ko = (kt + 2) * 64;
      #pragma unroll
      for (int g = 0; g < 2; ++g) GLD16(Ap[g] + ko, (char*)As + (sl << 1) + loff[g]);
      #pragma unroll
      for (int g = 0; g < 2; ++g) GLD16(Bp[g] + ko, (char*)Bs + (sl << 1) + loff[g]);
    }
    // x-tile prefetch: one chunk (rows kt*16..kt*16+15) per tile
    xv[kt] = *(const float4*)(xbase + (size_t)(kt * 16) * N);
    #pragma unroll
    for (int i2 = 0; i2 < 4; ++i2)
      #pragma unroll
      for (int j = 0; j < 2; ++j)
        acc[i2][j] = mfma16(af1[i2], bfr1[j], acc[i2][j]);
    if (kt == 0)      { VMC5; }
    else if (kt < 6)  { VMC6; }
    else if (kt == 6) { VMC2; }
    __builtin_amdgcn_s_barrier();            // next slot ready
  }

  // epilogue: acc -> LDS f32 [128][128] -> float4 out (bias + prefetched residual)
  float* Cf = (float*)AB;
  __syncthreads();
  #pragma unroll
  for (int j = 0; j < 2; ++j)
    #pragma unroll
    for (int i2 = 0; i2 < 4; ++i2)
      #pragma unroll
      for (int r = 0; r < 4; ++r)
        Cf[(wm * 64 + i2 * 16 + fq * 4 + r) * 128 + wn * 32 + j * 16 + fr] = acc[i2][j][r];
  __syncthreads();
  float4 b4;
  {
    int colb = bn * 128 + xcu * 4;
    b4 = *(const float4*)(bias + colb);
  }
  #pragma unroll
  for (int it = 0; it < 8; ++it) {
    int row = it * 16 + xrow;
    float4 c4 = ((const float4*)Cf)[row * 32 + xcu];
    size_t e = (size_t)(bm * 128 + row) * N + bn * 128 + xcu * 4;
    float4 o;
    o.x = xv[it].x + c4.x + b4.x;
    o.y = xv[it].y + c4.y + b4.y;
    o.z = xv[it].z + c4.z + b4.z;
    o.w = xv[it].w + c4.w + b4.w;
    *(float4*)(ofp + e) = o;
  }
}

// ---------------- banded attention: head-major input, async K staging ----------------
__global__ __launch_bounds__(256, 4) void attn_k(const unsigned short* __restrict__ qkv2,
                                                 unsigned short* __restrict__ obuf) {
  __shared__ unsigned short Ks[96 * 64];
  __shared__ unsigned short Vt[64 * 104];
  __shared__ unsigned short Ps[64 * 104];
  int tid = threadIdx.x;
  int lane = tid & 63, wave = tid >> 6;
  int fr = lane & 15, fq = lane >> 4;
  int bx = blockIdx.x;
  int t0 = ((((bx & 7) << 3) | (bx >> 3))) << 6;
  int hh = blockIdx.y;
  int bb = blockIdx.z;

  const unsigned short* Qs = qkv2 + (size_t)(bb * 8 + hh) * T_ * 64;
  const unsigned short* Kg = qkv2 + (size_t)(16 + bb * 8 + hh) * T_ * 64;
  const unsigned short* Vg = qkv2 + (size_t)(32 + bb * 8 + hh) * T_ * 64;

  #pragma unroll
  for (int it = 0; it < 3; ++it) {
    int c = tid + it * 256;
    int r = c >> 3, u = c & 7;
    int tg = t0 - BAND + r;
    tg = tg < 0 ? 0 : (tg >= T_ ? T_ - 1 : tg);
    GLD16(Kg + (size_t)tg * 64 + ((u ^ (r & 7)) << 3), Ks + c * 8);
    us8 vv = *(const us8*)(Vg + (size_t)tg * 64 + u * 8);
    #pragma unroll
    for (int j = 0; j < 8; ++j) Vt[(u * 8 + j) * 104 + r] = vv[j];
  }

  bf16x8 qf0, qf1;
  {
    int tq = t0 + wave * 16 + fr;
    const unsigned short* qp = Qs + (size_t)tq * 64 + fq * 8;
    qf0 = *(const bf16x8*)qp;
    qf1 = *(const bf16x8*)(qp + 32);
  }
  __syncthreads();

  f32x4 sa[6];
  #pragma unroll
  for (int c = 0; c < 6; ++c) sa[c] = (f32x4){0.f, 0.f, 0.f, 0.f};
  #pragma unroll
  for (int c = 0; c < 6; ++c) {
    bf16x8 k0 = *(const bf16x8*)(Ks + (c * 16 + fr) * 64 + ((fq ^ (fr & 7)) << 3));
    bf16x8 k1 = *(const bf16x8*)(Ks + (c * 16 + fr) * 64 + (((4 + fq) ^ (fr & 7)) << 3));
    sa[c] = mfma16(qf0, k0, sa[c]);
    sa[c] = mfma16(qf1, k1, sa[c]);
  }

  float inv[4];
  float pvv[6][4];
  #pragma unroll
  for (int r = 0; r < 4; ++r) {
    int tg = t0 + wave * 16 + fq * 4 + r;
    float m = -1e30f;
    #pragma unroll
    for (int c = 0; c < 6; ++c) {
      int cg = t0 - BAND + c * 16 + fr;
      bool ok = (cg >= tg - BAND) && (cg <= tg + BAND) && (cg >= 0) && (cg < T_);
      float v = ok ? sa[c][r] * 0.125f : -1e30f;
      pvv[c][r] = v;
      m = fmaxf(m, v);
    }
    #pragma unroll
    for (int o = 8; o; o >>= 1) m = fmaxf(m, __shfl_xor(m, o, 64));
    float s = 0.0f;
    #pragma unroll
    for (int c = 0; c < 6; ++c) {
      float e = exp2f((pvv[c][r] - m) * 1.44269504f);
      pvv[c][r] = e;
      s += e;
    }
    #pragma unroll
    for (int o = 8; o; o >>= 1) s += __shfl_xor(s, o, 64);
    inv[r] = 1.0f / s;
  }

  #pragma unroll
  for (int c = 0; c < 6; ++c)
    #pragma unroll
    for (int r = 0; r < 4; ++r)
      Ps[(wave * 16 + fq * 4 + r) * 104 + c * 16 + fr] = f2b(pvv[c][r]);

  __syncthreads();

  f32x4 oa[4];
  #pragma unroll
  for (int c2 = 0; c2 < 4; ++c2) oa[c2] = (f32x4){0.f, 0.f, 0.f, 0.f};
  #pragma unroll
  for (int kk = 0; kk < 3; ++kk) {
    bf16x8 pa = *(const bf16x8*)(Ps + (wave * 16 + fr) * 104 + kk * 32 + fq * 8);
    #pragma unroll
    for (int c2 = 0; c2 < 4; ++c2) {
      bf16x8 vb = *(const bf16x8*)(Vt + (c2 * 16 + fr) * 104 + kk * 32 + fq * 8);
      oa[c2] = mfma16(pa, vb, oa[c2]);
    }
  }

  __syncthreads();
  #pragma unroll
  for (int c2 = 0; c2 < 4; ++c2)
    #pragma unroll
    for (int r = 0; r < 4; ++r)
      Ps[(wave * 16 + fq * 4 + r) * 72 + c2 * 16 + fr] = f2b(oa[c2][r] * inv[r]);
  __syncthreads();
  size_t rowbase = (size_t)bb * T_;
  #pragma unroll
  for (int it = 0; it < 2; ++it) {
    int idx = it * 256 + tid;
    int row = idx >> 3, u = idx & 7;
    us8 v = *(const us8*)(Ps + row * 72 + u * 8);
    *(us8*)(obuf + (rowbase + t0 + row) * D_ + hh * 64 + u * 8) = v;
  }
}

extern "C" void kernel_launch(void* const* d_in, const int* in_sizes, int n_in,
                              void* d_out, int out_size, void* d_ws, size_t ws_size,
                              hipStream_t stream) {
  (void)in_sizes; (void)n_in; (void)out_size; (void)ws_size;
  const float* x     = (const float*)d_in[0];
  const float* ln_g  = (const float*)d_in[1];
  const float* ln_b  = (const float*)d_in[2];
  const float* w_in  = (const float*)d_in[3];
  const float* b_in  = (const float*)d_in[4];
  const float* w_out = (const float*)d_in[5];
  const float* b_out = (const float*)d_in[6];
  float* out = (float*)d_out;

  char* ws = (char*)d_ws;
  unsigned short* hb    = (unsigned short*)(ws);              // 8192*512   bf16
  unsigned short* winb  = (unsigned short*)(ws + 8388608);    // 1536*512   bf16
  unsigned short* woutb = (unsigned short*)(ws + 9961472);    // 512*512    bf16
  unsigned short* qkvb  = (unsigned short*)(ws + 10485760);   // 48*4096*64 bf16 (head-major)
  unsigned short* obf   = (unsigned short*)(ws + 35651584);   // 8192*512   bf16

  (void)hipFuncSetAttribute((const void*)gemm_qkv8,
                            hipFuncAttributeMaxDynamicSharedMemorySize, 114688);

  prep_k<<<3072, 256, 0, stream>>>(x, ln_g, ln_b, w_in, w_out, hb, winb, woutb);
  gemm_qkv8<<<256, 512, 114688, stream>>>(hb, winb, b_in, qkvb);
  attn_k<<<dim3(64, 8, 2), 256, 0, stream>>>(qkvb, obf);
  gemm_bt2<<<256, 512, 0, stream>>>(obf, woutb, b_out, x, out, 512, 512);
}

// Round 16
// 51.976 us; speedup vs baseline: 1.0147x; 1.0147x over previous
//
#include <hip/hip_runtime.h>
#include <hip/hip_bf16.h>

#define T_ 4096
#define D_ 512
#define H_ 8
#define BAND 16
#define G1_K 512

typedef float f32x4 __attribute__((ext_vector_type(4)));
typedef __bf16 bf16x8 __attribute__((ext_vector_type(8)));
typedef unsigned short us8 __attribute__((ext_vector_type(8)));
typedef unsigned short us4 __attribute__((ext_vector_type(4)));

__device__ __forceinline__ unsigned short f2b(float f) {
  union { float f; unsigned u; } v; v.f = f;
  unsigned r = v.u + 0x7fffu + ((v.u >> 16) & 1u);
  return (unsigned short)(r >> 16);
}

__device__ __forceinline__ f32x4 mfma16(bf16x8 a, bf16x8 b, f32x4 c) {
  return __builtin_amdgcn_mfma_f32_16x16x32_bf16(a, b, c, 0, 0, 0);
}

#define GLD16(gp, lp) __builtin_amdgcn_global_load_lds( \
    (const __attribute__((address_space(1))) void*)(gp), \
    (__attribute__((address_space(3))) void*)(lp), 16, 0, 0)

// ---------------- fused: weight fp32->bf16 cvt + LayerNorm ----------------
__global__ __launch_bounds__(256) void prep_k(const float* __restrict__ x,
                                              const float* __restrict__ g,
                                              const float* __restrict__ bt,
                                              const float* __restrict__ win,
                                              const float* __restrict__ wout,
                                              unsigned short* __restrict__ h,
                                              unsigned short* __restrict__ winb,
                                              unsigned short* __restrict__ woutb) {
  int bx = blockIdx.x;
  if (bx >= 2048) {
    int i = (bx - 2048) * 256 + threadIdx.x;
    const int n1 = 3 * D_ * D_ / 4;
    if (i < n1) {
      float4 v = ((const float4*)win)[i];
      us4 o; o.x = f2b(v.x); o.y = f2b(v.y); o.z = f2b(v.z); o.w = f2b(v.w);
      ((us4*)winb)[i] = o;
    } else {
      int j = i - n1;
      float4 v = ((const float4*)wout)[j];
      us4 o; o.x = f2b(v.x); o.y = f2b(v.y); o.z = f2b(v.z); o.w = f2b(v.w);
      ((us4*)woutb)[j] = o;
    }
    return;
  }
  int wave = threadIdx.x >> 6, lane = threadIdx.x & 63;
  size_t row = (size_t)bx * 4 + wave;
  const float4* xr = (const float4*)(x + row * D_);
  float4 a = xr[lane * 2], b = xr[lane * 2 + 1];
  float s = a.x + a.y + a.z + a.w + b.x + b.y + b.z + b.w;
  #pragma unroll
  for (int o = 32; o; o >>= 1) s += __shfl_xor(s, o, 64);
  float mu = s * (1.0f / D_);
  float d0 = a.x - mu, d1 = a.y - mu, d2 = a.z - mu, d3 = a.w - mu;
  float d4 = b.x - mu, d5 = b.y - mu, d6 = b.z - mu, d7 = b.w - mu;
  float q = d0*d0 + d1*d1 + d2*d2 + d3*d3 + d4*d4 + d5*d5 + d6*d6 + d7*d7;
  #pragma unroll
  for (int o = 32; o; o >>= 1) q += __shfl_xor(q, o, 64);
  float rstd = rsqrtf(q * (1.0f / D_) + 1e-5f);
  const float4* gr = (const float4*)g;
  const float4* br = (const float4*)bt;
  float4 g0 = gr[lane * 2], g1 = gr[lane * 2 + 1];
  float4 b0 = br[lane * 2], b1 = br[lane * 2 + 1];
  us8 o8;
  o8[0] = f2b(d0 * rstd * g0.x + b0.x);
  o8[1] = f2b(d1 * rstd * g0.y + b0.y);
  o8[2] = f2b(d2 * rstd * g0.z + b0.z);
  o8[3] = f2b(d3 * rstd * g0.w + b0.w);
  o8[4] = f2b(d4 * rstd * g1.x + b1.x);
  o8[5] = f2b(d5 * rstd * g1.y + b1.y);
  o8[6] = f2b(d6 * rstd * g1.z + b1.z);
  o8[7] = f2b(d7 * rstd * g1.w + b1.w);
  *((us8*)(h + row * D_) + lane) = o8;
}

// ============ GEMM1: 4-phase 256x192 BK=64, 8 waves, 256 blocks ============
#define SLOT_SZ 28672

__device__ __forceinline__ void stgA(const unsigned short* __restrict__ gb,
                                     unsigned short* lds, int slot, int h, int tt,
                                     int rl0, int u0, int su) {
  #pragma unroll
  for (int j = 0; j < 2; ++j) {
    int row = h * 128 + rl0 + 64 * j;
    GLD16(gb + (size_t)row * G1_K + tt * 64 + su, lds + slot * SLOT_SZ + row * 64 + u0 * 8);
  }
}
__device__ __forceinline__ void stgB(const unsigned short* __restrict__ gb,
                                     unsigned short* lds, int slot, int tt,
                                     int rl0, int u0, int su) {
  #pragma unroll
  for (int c = 0; c < 3; ++c) {
    int row = c * 64 + rl0;
    GLD16(gb + (size_t)row * G1_K + tt * 64 + su, lds + slot * SLOT_SZ + 16384 + row * 64 + u0 * 8);
  }
}

#define VMC4 asm volatile("s_waitcnt vmcnt(4)" ::: "memory")
#define VMC3 asm volatile("s_waitcnt vmcnt(3)" ::: "memory")
#define VMC0 asm volatile("s_waitcnt vmcnt(0)" ::: "memory")

// PH in {0,1}: m-frags 4*PH..4*PH+3. B-frags loaded at PH==0.
#define PHASE4(SLOT, PH, STAGE_STMT, WAIT_STMT) do {                                       \
    if ((PH) == 0) {                                                                       \
      _Pragma("unroll") for (int nf = 0; nf < 3; ++nf) {                                   \
        breg[nf][0] = *(const bf16x8*)(lds + (SLOT)*SLOT_SZ + boff + nf*1024 + swz0);      \
        breg[nf][1] = *(const bf16x8*)(lds + (SLOT)*SLOT_SZ + boff + nf*1024 + swz1);      \
      }                                                                                    \
    }                                                                                      \
    bf16x8 aA[4][2];                                                                       \
    _Pragma("unroll") for (int mi = 0; mi < 4; ++mi) {                                     \
      aA[mi][0] = *(const bf16x8*)(lds + (SLOT)*SLOT_SZ + aoff + (4*(PH)+mi)*1024 + swz0); \
      aA[mi][1] = *(const bf16x8*)(lds + (SLOT)*SLOT_SZ + aoff + (4*(PH)+mi)*1024 + swz1); \
    }                                                                                      \
    STAGE_STMT;                                                                            \
    __builtin_amdgcn_s_barrier();                                                          \
    asm volatile("s_waitcnt lgkmcnt(0)" ::: "memory");                                     \
    __builtin_amdgcn_sched_barrier(0);                                                     \
    __builtin_amdgcn_s_setprio(1);                                                         \
    _Pragma("unroll") for (int mi = 0; mi < 4; ++mi)                                       \
      _Pragma("unroll") for (int nf = 0; nf < 3; ++nf) {                                   \
        acc[4*(PH)+mi][nf] = mfma16(aA[mi][0], breg[nf][0], acc[4*(PH)+mi][nf]);           \
        acc[4*(PH)+mi][nf] = mfma16(aA[mi][1], breg[nf][1], acc[4*(PH)+mi][nf]);           \
      }                                                                                    \
    __builtin_amdgcn_s_setprio(0);                                                         \
    __builtin_amdgcn_sched_barrier(0);                                                     \
    WAIT_STMT;                                                                             \
    __builtin_amdgcn_s_barrier();                                                          \
  } while (0)

__global__ __launch_bounds__(512, 2) void gemm_qkv8(const unsigned short* __restrict__ A,
                                                    const unsigned short* __restrict__ Bw,
                                                    const float* __restrict__ bias,
                                                    unsigned short* __restrict__ C) {
  extern __shared__ char smem[];
  unsigned short* lds = (unsigned short*)smem;
  int tid = threadIdx.x;
  int lane = tid & 63, wave = tid >> 6;
  int wm = wave >> 2, wn = wave & 3;
  int fr = lane & 15, fq = lane >> 4;
  int d = blockIdx.x;
  int l = (d & 7) * 32 + (d >> 3);
  int bm = l >> 3, bn = l & 7;

  const unsigned short* Ag = A + (size_t)bm * 256 * G1_K;
  const unsigned short* Bg = Bw + (size_t)bn * 192 * G1_K;

  int rl0 = tid >> 3, u0 = tid & 7;
  int su = (u0 ^ (rl0 & 7)) * 8;

  int aoff = wm * 8192 + fr * 64;
  int boff = 16384 + (wn * 48 + fr) * 64;
  int swz0 = (fq ^ (fr & 7)) * 8;
  int swz1 = ((4 + fq) ^ (fr & 7)) * 8;

  f32x4 acc[8][3] = {};
  bf16x8 breg[3][2];

  stgB(Bg, lds, 0, 0, rl0, u0, su);
  stgA(Ag, lds, 0, 0, 0, rl0, u0, su);
  stgA(Ag, lds, 0, 1, 0, rl0, u0, su);
  stgB(Bg, lds, 1, 1, rl0, u0, su);
  VMC3;
  __builtin_amdgcn_s_barrier();

  #pragma unroll 1
  for (int i = 0; i < 3; ++i) {
    int t = 2 * i;
    PHASE4(0, 0, { stgA(Ag, lds, 1, 0, t + 1, rl0, u0, su);
                   stgA(Ag, lds, 1, 1, t + 1, rl0, u0, su); }, (void)0);
    PHASE4(0, 1, stgB(Bg, lds, 0, t + 2, rl0, u0, su), VMC3);
    PHASE4(1, 0, { stgA(Ag, lds, 0, 0, t + 2, rl0, u0, su);
                   stgA(Ag, lds, 0, 1, t + 2, rl0, u0, su); }, (void)0);
    PHASE4(1, 1, stgB(Bg, lds, 1, t + 3, rl0, u0, su), VMC3);
  }
  // tail: tiles 6,7
  PHASE4(0, 0, { stgA(Ag, lds, 1, 0, 7, rl0, u0, su);
                 stgA(Ag, lds, 1, 1, 7, rl0, u0, su); }, (void)0);
  PHASE4(0, 1, (void)0, VMC0);
  PHASE4(1, 0, (void)0, (void)0);
  PHASE4(1, 1, (void)0, (void)0);

  // epilogue: acc -> LDS bf16 [256][192] -> head-major coalesced stores
  int rl = wm * 128 + fq * 4;
  int cl = wn * 48 + fr;
  float bv[3];
  #pragma unroll
  for (int nf = 0; nf < 3; ++nf) bv[nf] = bias[bn * 192 + cl + nf * 16];
  __syncthreads();
  #pragma unroll
  for (int mf = 0; mf < 8; ++mf)
    #pragma unroll
    for (int nf = 0; nf < 3; ++nf)
      #pragma unroll
      for (int r = 0; r < 4; ++r)
        lds[(rl + mf * 16 + r) * 192 + cl + nf * 16] = f2b(acc[mf][nf][r] + bv[nf]);
  __syncthreads();
  int bb0 = (bm * 256) >> 12;
  int t00 = (bm * 256) & 4095;
  #pragma unroll
  for (int it = 0; it < 12; ++it) {
    int idx = it * 512 + tid;
    int row = idx / 24;
    int u = idx % 24;
    us8 v = *(const us8*)(lds + row * 192 + u * 8);
    int hs = bn * 3 + (u >> 3);
    int sec = hs >> 3, hd = hs & 7;
    size_t dst = ((size_t)(sec * 16 + bb0 * 8 + hd) * T_ + t00 + row) * 64 + (u & 7) * 8;
    *(us8*)(C + dst) = v;
  }
}

// ---------------- GEMM2 (R12-proven): 128x128, 512 threads, 2-slot prefetch ----------------
__global__ __launch_bounds__(512) void gemm_bt2(const unsigned short* __restrict__ A,
                                                const unsigned short* __restrict__ Bw,
                                                const float* __restrict__ bias,
                                                const float* __restrict__ xres,
                                                float* __restrict__ ofp,
                                                int N, int K) {
  __shared__ unsigned short AB[4 * 128 * 64];
  unsigned short* As = AB;
  unsigned short* Bs = AB + 16384;
  int tid = threadIdx.x;
  int lane = tid & 63;
  int wave = tid >> 6;
  int wm = wave >> 2, wn = wave & 3;
  int fr = lane & 15, fq = lane >> 4;
  int dd = blockIdx.x;
  int nbn = N >> 7;
  int l = (dd & 7) * (gridDim.x >> 3) + (dd >> 3);
  int bm = l / nbn, bn = l % nbn;

  const unsigned short* Ap[2];
  const unsigned short* Bp[2];
  int loff[2];
  #pragma unroll
  for (int g = 0; g < 2; ++g) {
    int s = g * 512 + tid;
    int row = s >> 3, u = s & 7;
    int uu = u ^ (row & 7);
    Ap[g] = A + (size_t)(bm * 128 + row) * K + uu * 8;
    Bp[g] = Bw + (size_t)(bn * 128 + row) * K + uu * 8;
    loff[g] = s * 16;
  }

  f32x4 acc[4][2] = {};

  #pragma unroll
  for (int g = 0; g < 2; ++g) GLD16(Ap[g], (char*)As + loff[g]);
  #pragma unroll
  for (int g = 0; g < 2; ++g) GLD16(Bp[g], (char*)Bs + loff[g]);
  #pragma unroll
  for (int g = 0; g < 2; ++g) GLD16(Ap[g] + 64, (char*)As + 16384 + loff[g]);
  #pragma unroll
  for (int g = 0; g < 2; ++g) GLD16(Bp[g] + 64, (char*)Bs + 16384 + loff[g]);
  VMC4;
  __builtin_amdgcn_s_barrier();

  #pragma unroll 1
  for (int kt = 0; kt < 8; ++kt) {
    int sl = (kt & 1) * 8192;
    bf16x8 af[4], bfr[2];
    #pragma unroll
    for (int i2 = 0; i2 < 4; ++i2) {
      int row = wm * 64 + i2 * 16 + fr;
      af[i2] = *(const bf16x8*)(As + sl + row * 64 + ((fq ^ (fr & 7)) << 3));
    }
    #pragma unroll
    for (int j = 0; j < 2; ++j) {
      int row = wn * 32 + j * 16 + fr;
      bfr[j] = *(const bf16x8*)(Bs + sl + row * 64 + ((fq ^ (fr & 7)) << 3));
    }
    #pragma unroll
    for (int i2 = 0; i2 < 4; ++i2)
      #pragma unroll
      for (int j = 0; j < 2; ++j)
        acc[i2][j] = mfma16(af[i2], bfr[j], acc[i2][j]);
    bf16x8 af1[4], bfr1[2];
    #pragma unroll
    for (int i2 = 0; i2 < 4; ++i2) {
      int row = wm * 64 + i2 * 16 + fr;
      af1[i2] = *(const bf16x8*)(As + sl + row * 64 + (((4 + fq) ^ (fr & 7)) << 3));
    }
    #pragma unroll
    for (int j = 0; j < 2; ++j) {
      int row = wn * 32 + j * 16 + fr;
      bfr1[j] = *(const bf16x8*)(Bs + sl + row * 64 + (((4 + fq) ^ (fr & 7)) << 3));
    }
    asm volatile("s_waitcnt lgkmcnt(0)" ::: "memory");
    __builtin_amdgcn_sched_barrier(0);
    __builtin_amdgcn_s_barrier();            // all waves done reading this slot
    if (kt < 6) {
      int ko = (kt + 2) * 64;
      #pragma unroll
      for (int g = 0; g < 2; ++g) GLD16(Ap[g] + ko, (char*)As + (sl << 1) + loff[g]);
      #pragma unroll
      for (int g = 0; g < 2; ++g) GLD16(Bp[g] + ko, (char*)Bs + (sl << 1) + loff[g]);
    }
    #pragma unroll
    for (int i2 = 0; i2 < 4; ++i2)
      #pragma unroll
      for (int j = 0; j < 2; ++j)
        acc[i2][j] = mfma16(af1[i2], bfr1[j], acc[i2][j]);
    if (kt < 6)      { VMC4; }
    else if (kt == 6){ VMC0; }
    __builtin_amdgcn_s_barrier();            // next slot ready
  }

  // epilogue: acc -> LDS f32 [128][128] -> float4 (bias + residual fused)
  float* Cf = (float*)AB;
  __syncthreads();
  #pragma unroll
  for (int j = 0; j < 2; ++j)
    #pragma unroll
    for (int i2 = 0; i2 < 4; ++i2)
      #pragma unroll
      for (int r = 0; r < 4; ++r)
        Cf[(wm * 64 + i2 * 16 + fq * 4 + r) * 128 + wn * 32 + j * 16 + fr] = acc[i2][j][r];
  __syncthreads();
  #pragma unroll
  for (int it = 0; it < 8; ++it) {
    int idx = it * 512 + tid;
    int row = idx >> 5, cu = idx & 31;
    float4 c4 = ((const float4*)Cf)[idx];
    int colb = bn * 128 + cu * 4;
    float4 b4 = *(const float4*)(bias + colb);
    size_t e = (size_t)(bm * 128 + row) * N + colb;
    float4 xv = *(const float4*)(xres + e);
    float4 o;
    o.x = xv.x + c4.x + b4.x;
    o.y = xv.y + c4.y + b4.y;
    o.z = xv.z + c4.z + b4.z;
    o.w = xv.w + c4.w + b4.w;
    *(float4*)(ofp + e) = o;
  }
}

// ---------------- banded attention: head-major input, async K staging ----------------
__global__ __launch_bounds__(256, 4) void attn_k(const unsigned short* __restrict__ qkv2,
                                                 unsigned short* __restrict__ obuf) {
  __shared__ unsigned short Ks[96 * 64];
  __shared__ unsigned short Vt[64 * 104];
  __shared__ unsigned short Ps[64 * 104];
  int tid = threadIdx.x;
  int lane = tid & 63, wave = tid >> 6;
  int fr = lane & 15, fq = lane >> 4;
  int bx = blockIdx.x;
  int t0 = ((((bx & 7) << 3) | (bx >> 3))) << 6;
  int hh = blockIdx.y;
  int bb = blockIdx.z;

  const unsigned short* Qs = qkv2 + (size_t)(bb * 8 + hh) * T_ * 64;
  const unsigned short* Kg = qkv2 + (size_t)(16 + bb * 8 + hh) * T_ * 64;
  const unsigned short* Vg = qkv2 + (size_t)(32 + bb * 8 + hh) * T_ * 64;

  #pragma unroll
  for (int it = 0; it < 3; ++it) {
    int c = tid + it * 256;
    int r = c >> 3, u = c & 7;
    int tg = t0 - BAND + r;
    tg = tg < 0 ? 0 : (tg >= T_ ? T_ - 1 : tg);
    GLD16(Kg + (size_t)tg * 64 + ((u ^ (r & 7)) << 3), Ks + c * 8);
    us8 vv = *(const us8*)(Vg + (size_t)tg * 64 + u * 8);
    #pragma unroll
    for (int j = 0; j < 8; ++j) Vt[(u * 8 + j) * 104 + r] = vv[j];
  }

  bf16x8 qf0, qf1;
  {
    int tq = t0 + wave * 16 + fr;
    const unsigned short* qp = Qs + (size_t)tq * 64 + fq * 8;
    qf0 = *(const bf16x8*)qp;
    qf1 = *(const bf16x8*)(qp + 32);
  }
  __syncthreads();

  f32x4 sa[6];
  #pragma unroll
  for (int c = 0; c < 6; ++c) sa[c] = (f32x4){0.f, 0.f, 0.f, 0.f};
  #pragma unroll
  for (int c = 0; c < 6; ++c) {
    bf16x8 k0 = *(const bf16x8*)(Ks + (c * 16 + fr) * 64 + ((fq ^ (fr & 7)) << 3));
    bf16x8 k1 = *(const bf16x8*)(Ks + (c * 16 + fr) * 64 + (((4 + fq) ^ (fr & 7)) << 3));
    sa[c] = mfma16(qf0, k0, sa[c]);
    sa[c] = mfma16(qf1, k1, sa[c]);
  }

  float inv[4];
  float pvv[6][4];
  #pragma unroll
  for (int r = 0; r < 4; ++r) {
    int tg = t0 + wave * 16 + fq * 4 + r;
    float m = -1e30f;
    #pragma unroll
    for (int c = 0; c < 6; ++c) {
      int cg = t0 - BAND + c * 16 + fr;
      bool ok = (cg >= tg - BAND) && (cg <= tg + BAND) && (cg >= 0) && (cg < T_);
      float v = ok ? sa[c][r] * 0.125f : -1e30f;
      pvv[c][r] = v;
      m = fmaxf(m, v);
    }
    #pragma unroll
    for (int o = 8; o; o >>= 1) m = fmaxf(m, __shfl_xor(m, o, 64));
    float s = 0.0f;
    #pragma unroll
    for (int c = 0; c < 6; ++c) {
      float e = exp2f((pvv[c][r] - m) * 1.44269504f);
      pvv[c][r] = e;
      s += e;
    }
    #pragma unroll
    for (int o = 8; o; o >>= 1) s += __shfl_xor(s, o, 64);
    inv[r] = 1.0f / s;
  }

  #pragma unroll
  for (int c = 0; c < 6; ++c)
    #pragma unroll
    for (int r = 0; r < 4; ++r)
      Ps[(wave * 16 + fq * 4 + r) * 104 + c * 16 + fr] = f2b(pvv[c][r]);

  __syncthreads();

  f32x4 oa[4];
  #pragma unroll
  for (int c2 = 0; c2 < 4; ++c2) oa[c2] = (f32x4){0.f, 0.f, 0.f, 0.f};
  #pragma unroll
  for (int kk = 0; kk < 3; ++kk) {
    bf16x8 pa = *(const bf16x8*)(Ps + (wave * 16 + fr) * 104 + kk * 32 + fq * 8);
    #pragma unroll
    for (int c2 = 0; c2 < 4; ++c2) {
      bf16x8 vb = *(const bf16x8*)(Vt + (c2 * 16 + fr) * 104 + kk * 32 + fq * 8);
      oa[c2] = mfma16(pa, vb, oa[c2]);
    }
  }

  __syncthreads();
  #pragma unroll
  for (int c2 = 0; c2 < 4; ++c2)
    #pragma unroll
    for (int r = 0; r < 4; ++r)
      Ps[(wave * 16 + fq * 4 + r) * 72 + c2 * 16 + fr] = f2b(oa[c2][r] * inv[r]);
  __syncthreads();
  size_t rowbase = (size_t)bb * T_;
  #pragma unroll
  for (int it = 0; it < 2; ++it) {
    int idx = it * 256 + tid;
    int row = idx >> 3, u = idx & 7;
    us8 v = *(const us8*)(Ps + row * 72 + u * 8);
    *(us8*)(obuf + (rowbase + t0 + row) * D_ + hh * 64 + u * 8) = v;
  }
}

extern "C" void kernel_launch(void* const* d_in, const int* in_sizes, int n_in,
                              void* d_out, int out_size, void* d_ws, size_t ws_size,
                              hipStream_t stream) {
  (void)in_sizes; (void)n_in; (void)out_size; (void)ws_size;
  const float* x     = (const float*)d_in[0];
  const float* ln_g  = (const float*)d_in[1];
  const float* ln_b  = (const float*)d_in[2];
  const float* w_in  = (const float*)d_in[3];
  const float* b_in  = (const float*)d_in[4];
  const float* w_out = (const float*)d_in[5];
  const float* b_out = (const float*)d_in[6];
  float* out = (float*)d_out;

  char* ws = (char*)d_ws;
  unsigned short* hb    = (unsigned short*)(ws);              // 8192*512   bf16
  unsigned short* winb  = (unsigned short*)(ws + 8388608);    // 1536*512   bf16
  unsigned short* woutb = (unsigned short*)(ws + 9961472);    // 512*512    bf16
  unsigned short* qkvb  = (unsigned short*)(ws + 10485760);   // 48*4096*64 bf16 (head-major)
  unsigned short* obf   = (unsigned short*)(ws + 35651584);   // 8192*512   bf16

  (void)hipFuncSetAttribute((const void*)gemm_qkv8,
                            hipFuncAttributeMaxDynamicSharedMemorySize, 114688);

  prep_k<<<3072, 256, 0, stream>>>(x, ln_g, ln_b, w_in, w_out, hb, winb, woutb);
  gemm_qkv8<<<256, 512, 114688, stream>>>(hb, winb, b_in, qkvb);
  attn_k<<<dim3(64, 8, 2), 256, 0, stream>>>(qkvb, obf);
  gemm_bt2<<<256, 512, 0, stream>>>(obf, woutb, b_out, x, out, 512, 512);
}

// Round 17
// 51.445 us; speedup vs baseline: 1.0252x; 1.0103x over previous
//
#include <hip/hip_runtime.h>
#include <hip/hip_bf16.h>

#define T_ 4096
#define D_ 512
#define H_ 8
#define BAND 16
#define G1_K 512

typedef float f32x4 __attribute__((ext_vector_type(4)));
typedef __bf16 bf16x8 __attribute__((ext_vector_type(8)));
typedef unsigned short us8 __attribute__((ext_vector_type(8)));
typedef unsigned short us4 __attribute__((ext_vector_type(4)));

__device__ __forceinline__ unsigned short f2b(float f) {
  union { float f; unsigned u; } v; v.f = f;
  unsigned r = v.u + 0x7fffu + ((v.u >> 16) & 1u);
  return (unsigned short)(r >> 16);
}

__device__ __forceinline__ f32x4 mfma16(bf16x8 a, bf16x8 b, f32x4 c) {
  return __builtin_amdgcn_mfma_f32_16x16x32_bf16(a, b, c, 0, 0, 0);
}

#define GLD16(gp, lp) __builtin_amdgcn_global_load_lds( \
    (const __attribute__((address_space(1))) void*)(gp), \
    (__attribute__((address_space(3))) void*)(lp), 16, 0, 0)

// ---------------- fused: weight fp32->bf16 cvt + LayerNorm ----------------
__global__ __launch_bounds__(256) void prep_k(const float* __restrict__ x,
                                              const float* __restrict__ g,
                                              const float* __restrict__ bt,
                                              const float* __restrict__ win,
                                              const float* __restrict__ wout,
                                              unsigned short* __restrict__ h,
                                              unsigned short* __restrict__ winb,
                                              unsigned short* __restrict__ woutb) {
  int bx = blockIdx.x;
  if (bx >= 2048) {
    int i = (bx - 2048) * 256 + threadIdx.x;
    const int n1 = 3 * D_ * D_ / 4;
    if (i < n1) {
      float4 v = ((const float4*)win)[i];
      us4 o; o.x = f2b(v.x); o.y = f2b(v.y); o.z = f2b(v.z); o.w = f2b(v.w);
      ((us4*)winb)[i] = o;
    } else {
      int j = i - n1;
      float4 v = ((const float4*)wout)[j];
      us4 o; o.x = f2b(v.x); o.y = f2b(v.y); o.z = f2b(v.z); o.w = f2b(v.w);
      ((us4*)woutb)[j] = o;
    }
    return;
  }
  int wave = threadIdx.x >> 6, lane = threadIdx.x & 63;
  size_t row = (size_t)bx * 4 + wave;
  const float4* xr = (const float4*)(x + row * D_);
  float4 a = xr[lane * 2], b = xr[lane * 2 + 1];
  float s = a.x + a.y + a.z + a.w + b.x + b.y + b.z + b.w;
  #pragma unroll
  for (int o = 32; o; o >>= 1) s += __shfl_xor(s, o, 64);
  float mu = s * (1.0f / D_);
  float d0 = a.x - mu, d1 = a.y - mu, d2 = a.z - mu, d3 = a.w - mu;
  float d4 = b.x - mu, d5 = b.y - mu, d6 = b.z - mu, d7 = b.w - mu;
  float q = d0*d0 + d1*d1 + d2*d2 + d3*d3 + d4*d4 + d5*d5 + d6*d6 + d7*d7;
  #pragma unroll
  for (int o = 32; o; o >>= 1) q += __shfl_xor(q, o, 64);
  float rstd = rsqrtf(q * (1.0f / D_) + 1e-5f);
  const float4* gr = (const float4*)g;
  const float4* br = (const float4*)bt;
  float4 g0 = gr[lane * 2], g1 = gr[lane * 2 + 1];
  float4 b0 = br[lane * 2], b1 = br[lane * 2 + 1];
  us8 o8;
  o8[0] = f2b(d0 * rstd * g0.x + b0.x);
  o8[1] = f2b(d1 * rstd * g0.y + b0.y);
  o8[2] = f2b(d2 * rstd * g0.z + b0.z);
  o8[3] = f2b(d3 * rstd * g0.w + b0.w);
  o8[4] = f2b(d4 * rstd * g1.x + b1.x);
  o8[5] = f2b(d5 * rstd * g1.y + b1.y);
  o8[6] = f2b(d6 * rstd * g1.z + b1.z);
  o8[7] = f2b(d7 * rstd * g1.w + b1.w);
  *((us8*)(h + row * D_) + lane) = o8;
}

// ============ GEMM1: 4-phase 256x192 BK=64, 8 waves, 256 blocks ============
#define SLOT_SZ 28672

__device__ __forceinline__ void stgA(const unsigned short* __restrict__ gb,
                                     unsigned short* lds, int slot, int h, int tt,
                                     int rl0, int u0, int su) {
  #pragma unroll
  for (int j = 0; j < 2; ++j) {
    int row = h * 128 + rl0 + 64 * j;
    GLD16(gb + (size_t)row * G1_K + tt * 64 + su, lds + slot * SLOT_SZ + row * 64 + u0 * 8);
  }
}
__device__ __forceinline__ void stgB(const unsigned short* __restrict__ gb,
                                     unsigned short* lds, int slot, int tt,
                                     int rl0, int u0, int su) {
  #pragma unroll
  for (int c = 0; c < 3; ++c) {
    int row = c * 64 + rl0;
    GLD16(gb + (size_t)row * G1_K + tt * 64 + su, lds + slot * SLOT_SZ + 16384 + row * 64 + u0 * 8);
  }
}

#define VMC6 asm volatile("s_waitcnt vmcnt(6)" ::: "memory")
#define VMC3 asm volatile("s_waitcnt vmcnt(3)" ::: "memory")
#define VMC0 asm volatile("s_waitcnt vmcnt(0)" ::: "memory")

// PH in {0,1}: m-frags 4*PH..4*PH+3. B-frags loaded at PH==0.
#define PHASE4(SLOT, PH, STAGE_STMT, WAIT_STMT) do {                                       \
    if ((PH) == 0) {                                                                       \
      _Pragma("unroll") for (int nf = 0; nf < 3; ++nf) {                                   \
        breg[nf][0] = *(const bf16x8*)(lds + (SLOT)*SLOT_SZ + boff + nf*1024 + swz0);      \
        breg[nf][1] = *(const bf16x8*)(lds + (SLOT)*SLOT_SZ + boff + nf*1024 + swz1);      \
      }                                                                                    \
    }                                                                                      \
    bf16x8 aA[4][2];                                                                       \
    _Pragma("unroll") for (int mi = 0; mi < 4; ++mi) {                                     \
      aA[mi][0] = *(const bf16x8*)(lds + (SLOT)*SLOT_SZ + aoff + (4*(PH)+mi)*1024 + swz0); \
      aA[mi][1] = *(const bf16x8*)(lds + (SLOT)*SLOT_SZ + aoff + (4*(PH)+mi)*1024 + swz1); \
    }                                                                                      \
    STAGE_STMT;                                                                            \
    __builtin_amdgcn_s_barrier();                                                          \
    asm volatile("s_waitcnt lgkmcnt(0)" ::: "memory");                                     \
    __builtin_amdgcn_sched_barrier(0);                                                     \
    __builtin_amdgcn_s_setprio(1);                                                         \
    _Pragma("unroll") for (int mi = 0; mi < 4; ++mi)                                       \
      _Pragma("unroll") for (int nf = 0; nf < 3; ++nf) {                                   \
        acc[4*(PH)+mi][nf] = mfma16(aA[mi][0], breg[nf][0], acc[4*(PH)+mi][nf]);           \
        acc[4*(PH)+mi][nf] = mfma16(aA[mi][1], breg[nf][1], acc[4*(PH)+mi][nf]);           \
      }                                                                                    \
    __builtin_amdgcn_s_setprio(0);                                                         \
    __builtin_amdgcn_sched_barrier(0);                                                     \
    WAIT_STMT;                                                                             \
    __builtin_amdgcn_s_barrier();                                                          \
  } while (0)

__global__ __launch_bounds__(512, 2) void gemm_qkv8(const unsigned short* __restrict__ A,
                                                    const unsigned short* __restrict__ Bw,
                                                    const float* __restrict__ bias,
                                                    unsigned short* __restrict__ C) {
  extern __shared__ char smem[];
  unsigned short* lds = (unsigned short*)smem;
  int tid = threadIdx.x;
  int lane = tid & 63, wave = tid >> 6;
  int wm = wave >> 2, wn = wave & 3;
  int fr = lane & 15, fq = lane >> 4;
  int d = blockIdx.x;
  int l = (d & 7) * 32 + (d >> 3);
  int bm = l >> 3, bn = l & 7;

  const unsigned short* Ag = A + (size_t)bm * 256 * G1_K;
  const unsigned short* Bg = Bw + (size_t)bn * 192 * G1_K;

  int rl0 = tid >> 3, u0 = tid & 7;
  int su = (u0 ^ (rl0 & 7)) * 8;

  int aoff = wm * 8192 + fr * 64;
  int boff = 16384 + (wn * 48 + fr) * 64;
  int swz0 = (fq ^ (fr & 7)) * 8;
  int swz1 = ((4 + fq) ^ (fr & 7)) * 8;

  f32x4 acc[8][3] = {};
  bf16x8 breg[3][2];

  stgB(Bg, lds, 0, 0, rl0, u0, su);
  stgA(Ag, lds, 0, 0, 0, rl0, u0, su);
  stgA(Ag, lds, 0, 1, 0, rl0, u0, su);
  stgB(Bg, lds, 1, 1, rl0, u0, su);
  VMC3;
  __builtin_amdgcn_s_barrier();

  #pragma unroll 1
  for (int i = 0; i < 3; ++i) {
    int t = 2 * i;
    PHASE4(0, 0, { stgA(Ag, lds, 1, 0, t + 1, rl0, u0, su);
                   stgA(Ag, lds, 1, 1, t + 1, rl0, u0, su); }, (void)0);
    PHASE4(0, 1, stgB(Bg, lds, 0, t + 2, rl0, u0, su), VMC3);
    PHASE4(1, 0, { stgA(Ag, lds, 0, 0, t + 2, rl0, u0, su);
                   stgA(Ag, lds, 0, 1, t + 2, rl0, u0, su); }, (void)0);
    PHASE4(1, 1, stgB(Bg, lds, 1, t + 3, rl0, u0, su), VMC3);
  }
  // tail: tiles 6,7
  PHASE4(0, 0, { stgA(Ag, lds, 1, 0, 7, rl0, u0, su);
                 stgA(Ag, lds, 1, 1, 7, rl0, u0, su); }, (void)0);
  PHASE4(0, 1, (void)0, VMC0);
  PHASE4(1, 0, (void)0, (void)0);
  PHASE4(1, 1, (void)0, (void)0);

  // epilogue: acc -> LDS bf16 [256][192] -> head-major coalesced stores
  int rl = wm * 128 + fq * 4;
  int cl = wn * 48 + fr;
  float bv[3];
  #pragma unroll
  for (int nf = 0; nf < 3; ++nf) bv[nf] = bias[bn * 192 + cl + nf * 16];
  __syncthreads();
  #pragma unroll
  for (int mf = 0; mf < 8; ++mf)
    #pragma unroll
    for (int nf = 0; nf < 3; ++nf)
      #pragma unroll
      for (int r = 0; r < 4; ++r)
        lds[(rl + mf * 16 + r) * 192 + cl + nf * 16] = f2b(acc[mf][nf][r] + bv[nf]);
  __syncthreads();
  int bb0 = (bm * 256) >> 12;
  int t00 = (bm * 256) & 4095;
  #pragma unroll
  for (int it = 0; it < 12; ++it) {
    int idx = it * 512 + tid;
    int row = idx / 24;
    int u = idx % 24;
    us8 v = *(const us8*)(lds + row * 192 + u * 8);
    int hs = bn * 3 + (u >> 3);
    int sec = hs >> 3, hd = hs & 7;
    size_t dst = ((size_t)(sec * 16 + bb0 * 8 + hd) * T_ + t00 + row) * 64 + (u & 7) * 8;
    *(us8*)(C + dst) = v;
  }
}

// ---------------- GEMM2: 64x128 tile, 256 threads (4 waves 2x2), 512 blocks = 2/CU ----------------
// Per slot (elems): A[64][64] at 0, B[128][64] at 4096; SLOT=12288; 2 slots = 48KB LDS.
// Ledger: 6 GLD16/thread/tile; prologue 12 -> VMC6; steady VMC6; kt==6 VMC0.
__global__ __launch_bounds__(256) void gemm_bt2(const unsigned short* __restrict__ A,
                                                const unsigned short* __restrict__ Bw,
                                                const float* __restrict__ bias,
                                                const float* __restrict__ xres,
                                                float* __restrict__ ofp,
                                                int N, int K) {
  __shared__ unsigned short AB[2 * 12288];      // epilogue reuse: f32[64][128] = 32KB
  int tid = threadIdx.x;
  int lane = tid & 63;
  int wave = tid >> 6;                 // 0..3
  int wm = wave >> 1, wn = wave & 1;   // wave tile: 32 rows x 64 cols
  int fr = lane & 15, fq = lane >> 4;
  int dd = blockIdx.x;
  int nbn = N >> 7;                    // 4
  int l = (dd & 7) * (gridDim.x >> 3) + (dd >> 3);
  int bm = l / nbn, bn = l % nbn;      // bm 0..127, bn 0..3

  const unsigned short* Ap[2];
  int aoffl[2];
  #pragma unroll
  for (int g = 0; g < 2; ++g) {
    int s = g * 256 + tid;             // 0..511 (A: 512 us8-units)
    int row = s >> 3, u = s & 7;
    int uu = u ^ (row & 7);
    Ap[g] = A + (size_t)(bm * 64 + row) * K + uu * 8;
    aoffl[g] = row * 64 + u * 8;       // elem offset within slot's A region
  }
  const unsigned short* Bp[4];
  int boffl[4];
  #pragma unroll
  for (int g = 0; g < 4; ++g) {
    int s = g * 256 + tid;             // 0..1023 (B: 1024 us8-units)
    int row = s >> 3, u = s & 7;
    int uu = u ^ (row & 7);
    Bp[g] = Bw + (size_t)(bn * 128 + row) * K + uu * 8;
    boffl[g] = 4096 + row * 64 + u * 8;
  }

  f32x4 acc[2][4] = {};

  // prologue: stage t0 -> slot0, t1 -> slot1 (6 loads/thread per tile)
  #pragma unroll
  for (int g = 0; g < 2; ++g) GLD16(Ap[g], AB + aoffl[g]);
  #pragma unroll
  for (int g = 0; g < 4; ++g) GLD16(Bp[g], AB + boffl[g]);
  #pragma unroll
  for (int g = 0; g < 2; ++g) GLD16(Ap[g] + 64, AB + 12288 + aoffl[g]);
  #pragma unroll
  for (int g = 0; g < 4; ++g) GLD16(Bp[g] + 64, AB + 12288 + boffl[g]);
  VMC6;
  __builtin_amdgcn_s_barrier();

  #pragma unroll 1
  for (int kt = 0; kt < 8; ++kt) {
    int sl = (kt & 1) * 12288;
    // kk0 frags + MFMA
    bf16x8 af[2], bfr[4];
    #pragma unroll
    for (int i2 = 0; i2 < 2; ++i2) {
      int row = wm * 32 + i2 * 16 + fr;
      af[i2] = *(const bf16x8*)(AB + sl + row * 64 + ((fq ^ (fr & 7)) << 3));
    }
    #pragma unroll
    for (int j = 0; j < 4; ++j) {
      int row = wn * 64 + j * 16 + fr;
      bfr[j] = *(const bf16x8*)(AB + sl + 4096 + row * 64 + ((fq ^ (fr & 7)) << 3));
    }
    #pragma unroll
    for (int i2 = 0; i2 < 2; ++i2)
      #pragma unroll
      for (int j = 0; j < 4; ++j)
        acc[i2][j] = mfma16(af[i2], bfr[j], acc[i2][j]);
    // kk1 frags
    bf16x8 af1[2], bfr1[4];
    #pragma unroll
    for (int i2 = 0; i2 < 2; ++i2) {
      int row = wm * 32 + i2 * 16 + fr;
      af1[i2] = *(const bf16x8*)(AB + sl + row * 64 + (((4 + fq) ^ (fr & 7)) << 3));
    }
    #pragma unroll
    for (int j = 0; j < 4; ++j) {
      int row = wn * 64 + j * 16 + fr;
      bfr1[j] = *(const bf16x8*)(AB + sl + 4096 + row * 64 + (((4 + fq) ^ (fr & 7)) << 3));
    }
    asm volatile("s_waitcnt lgkmcnt(0)" ::: "memory");
    __builtin_amdgcn_sched_barrier(0);
    __builtin_amdgcn_s_barrier();            // all waves done reading this slot
    if (kt < 6) {
      int ko = (kt + 2) * 64;
      #pragma unroll
      for (int g = 0; g < 2; ++g) GLD16(Ap[g] + ko, AB + sl + aoffl[g]);
      #pragma unroll
      for (int g = 0; g < 4; ++g) GLD16(Bp[g] + ko, AB + sl + boffl[g]);
    }
    #pragma unroll
    for (int i2 = 0; i2 < 2; ++i2)
      #pragma unroll
      for (int j = 0; j < 4; ++j)
        acc[i2][j] = mfma16(af1[i2], bfr1[j], acc[i2][j]);
    if (kt < 6)      { VMC6; }
    else if (kt == 6){ VMC0; }
    __builtin_amdgcn_s_barrier();            // next slot ready
  }

  // epilogue: acc -> LDS f32 [64][128] -> float4 (bias + residual fused)
  float* Cf = (float*)AB;
  __syncthreads();
  #pragma unroll
  for (int j = 0; j < 4; ++j)
    #pragma unroll
    for (int i2 = 0; i2 < 2; ++i2)
      #pragma unroll
      for (int r = 0; r < 4; ++r)
        Cf[(wm * 32 + i2 * 16 + fq * 4 + r) * 128 + wn * 64 + j * 16 + fr] = acc[i2][j][r];
  __syncthreads();
  #pragma unroll
  for (int it = 0; it < 8; ++it) {
    int idx = it * 256 + tid;          // float4 units: 32/row, 64 rows
    int row = idx >> 5, cu = idx & 31;
    float4 c4 = ((const float4*)Cf)[idx];
    int colb = bn * 128 + cu * 4;
    float4 b4 = *(const float4*)(bias + colb);
    size_t e = (size_t)(bm * 64 + row) * N + colb;
    float4 xv = *(const float4*)(xres + e);
    float4 o;
    o.x = xv.x + c4.x + b4.x;
    o.y = xv.y + c4.y + b4.y;
    o.z = xv.z + c4.z + b4.z;
    o.w = xv.w + c4.w + b4.w;
    *(float4*)(ofp + e) = o;
  }
}

// ---------------- banded attention: head-major input, async K staging ----------------
__global__ __launch_bounds__(256, 4) void attn_k(const unsigned short* __restrict__ qkv2,
                                                 unsigned short* __restrict__ obuf) {
  __shared__ unsigned short Ks[96 * 64];
  __shared__ unsigned short Vt[64 * 104];
  __shared__ unsigned short Ps[64 * 104];
  int tid = threadIdx.x;
  int lane = tid & 63, wave = tid >> 6;
  int fr = lane & 15, fq = lane >> 4;
  int bx = blockIdx.x;
  int t0 = ((((bx & 7) << 3) | (bx >> 3))) << 6;
  int hh = blockIdx.y;
  int bb = blockIdx.z;

  const unsigned short* Qs = qkv2 + (size_t)(bb * 8 + hh) * T_ * 64;
  const unsigned short* Kg = qkv2 + (size_t)(16 + bb * 8 + hh) * T_ * 64;
  const unsigned short* Vg = qkv2 + (size_t)(32 + bb * 8 + hh) * T_ * 64;

  #pragma unroll
  for (int it = 0; it < 3; ++it) {
    int c = tid + it * 256;
    int r = c >> 3, u = c & 7;
    int tg = t0 - BAND + r;
    tg = tg < 0 ? 0 : (tg >= T_ ? T_ - 1 : tg);
    GLD16(Kg + (size_t)tg * 64 + ((u ^ (r & 7)) << 3), Ks + c * 8);
    us8 vv = *(const us8*)(Vg + (size_t)tg * 64 + u * 8);
    #pragma unroll
    for (int j = 0; j < 8; ++j) Vt[(u * 8 + j) * 104 + r] = vv[j];
  }

  bf16x8 qf0, qf1;
  {
    int tq = t0 + wave * 16 + fr;
    const unsigned short* qp = Qs + (size_t)tq * 64 + fq * 8;
    qf0 = *(const bf16x8*)qp;
    qf1 = *(const bf16x8*)(qp + 32);
  }
  __syncthreads();

  f32x4 sa[6];
  #pragma unroll
  for (int c = 0; c < 6; ++c) sa[c] = (f32x4){0.f, 0.f, 0.f, 0.f};
  #pragma unroll
  for (int c = 0; c < 6; ++c) {
    bf16x8 k0 = *(const bf16x8*)(Ks + (c * 16 + fr) * 64 + ((fq ^ (fr & 7)) << 3));
    bf16x8 k1 = *(const bf16x8*)(Ks + (c * 16 + fr) * 64 + (((4 + fq) ^ (fr & 7)) << 3));
    sa[c] = mfma16(qf0, k0, sa[c]);
    sa[c] = mfma16(qf1, k1, sa[c]);
  }

  float inv[4];
  float pvv[6][4];
  #pragma unroll
  for (int r = 0; r < 4; ++r) {
    int tg = t0 + wave * 16 + fq * 4 + r;
    float m = -1e30f;
    #pragma unroll
    for (int c = 0; c < 6; ++c) {
      int cg = t0 - BAND + c * 16 + fr;
      bool ok = (cg >= tg - BAND) && (cg <= tg + BAND) && (cg >= 0) && (cg < T_);
      float v = ok ? sa[c][r] * 0.125f : -1e30f;
      pvv[c][r] = v;
      m = fmaxf(m, v);
    }
    #pragma unroll
    for (int o = 8; o; o >>= 1) m = fmaxf(m, __shfl_xor(m, o, 64));
    float s = 0.0f;
    #pragma unroll
    for (int c = 0; c < 6; ++c) {
      float e = exp2f((pvv[c][r] - m) * 1.44269504f);
      pvv[c][r] = e;
      s += e;
    }
    #pragma unroll
    for (int o = 8; o; o >>= 1) s += __shfl_xor(s, o, 64);
    inv[r] = 1.0f / s;
  }

  #pragma unroll
  for (int c = 0; c < 6; ++c)
    #pragma unroll
    for (int r = 0; r < 4; ++r)
      Ps[(wave * 16 + fq * 4 + r) * 104 + c * 16 + fr] = f2b(pvv[c][r]);

  __syncthreads();

  f32x4 oa[4];
  #pragma unroll
  for (int c2 = 0; c2 < 4; ++c2) oa[c2] = (f32x4){0.f, 0.f, 0.f, 0.f};
  #pragma unroll
  for (int kk = 0; kk < 3; ++kk) {
    bf16x8 pa = *(const bf16x8*)(Ps + (wave * 16 + fr) * 104 + kk * 32 + fq * 8);
    #pragma unroll
    for (int c2 = 0; c2 < 4; ++c2) {
      bf16x8 vb = *(const bf16x8*)(Vt + (c2 * 16 + fr) * 104 + kk * 32 + fq * 8);
      oa[c2] = mfma16(pa, vb, oa[c2]);
    }
  }

  __syncthreads();
  #pragma unroll
  for (int c2 = 0; c2 < 4; ++c2)
    #pragma unroll
    for (int r = 0; r < 4; ++r)
      Ps[(wave * 16 + fq * 4 + r) * 72 + c2 * 16 + fr] = f2b(oa[c2][r] * inv[r]);
  __syncthreads();
  size_t rowbase = (size_t)bb * T_;
  #pragma unroll
  for (int it = 0; it < 2; ++it) {
    int idx = it * 256 + tid;
    int row = idx >> 3, u = idx & 7;
    us8 v = *(const us8*)(Ps + row * 72 + u * 8);
    *(us8*)(obuf + (rowbase + t0 + row) * D_ + hh * 64 + u * 8) = v;
  }
}

extern "C" void kernel_launch(void* const* d_in, const int* in_sizes, int n_in,
                              void* d_out, int out_size, void* d_ws, size_t ws_size,
                              hipStream_t stream) {
  (void)in_sizes; (void)n_in; (void)out_size; (void)ws_size;
  const float* x     = (const float*)d_in[0];
  const float* ln_g  = (const float*)d_in[1];
  const float* ln_b  = (const float*)d_in[2];
  const float* w_in  = (const float*)d_in[3];
  const float* b_in  = (const float*)d_in[4];
  const float* w_out = (const float*)d_in[5];
  const float* b_out = (const float*)d_in[6];
  float* out = (float*)d_out;

  char* ws = (char*)d_ws;
  unsigned short* hb    = (unsigned short*)(ws);              // 8192*512   bf16
  unsigned short* winb  = (unsigned short*)(ws + 8388608);    // 1536*512   bf16
  unsigned short* woutb = (unsigned short*)(ws + 9961472);    // 512*512    bf16
  unsigned short* qkvb  = (unsigned short*)(ws + 10485760);   // 48*4096*64 bf16 (head-major)
  unsigned short* obf   = (unsigned short*)(ws + 35651584);   // 8192*512   bf16

  (void)hipFuncSetAttribute((const void*)gemm_qkv8,
                            hipFuncAttributeMaxDynamicSharedMemorySize, 114688);

  prep_k<<<3072, 256, 0, stream>>>(x, ln_g, ln_b, w_in, w_out, hb, winb, woutb);
  gemm_qkv8<<<256, 512, 114688, stream>>>(hb, winb, b_in, qkvb);
  attn_k<<<dim3(64, 8, 2), 256, 0, stream>>>(qkvb, obf);
  gemm_bt2<<<512, 256, 0, stream>>>(obf, woutb, b_out, x, out, 512, 512);
}